// Round 1
// baseline (803.384 us; speedup 1.0000x reference)
//
#include <hip/hip_runtime.h>
#include <math.h>

#define NN   512
#define NV   8
#define PAD  132     // LDS row stride (floats) for [32][128] activation tiles
#define CH   32      // receivers per chunk
#define NCH  16      // chunks per sender (16*32 = 512 rows, r==s masked)

#define C1 0.06154574548966636f   // 1/sqrt(264)
#define C2 0.08838834764831845f   // 1/sqrt(128)
#define SQRT3 1.7320508075688772f

__device__ __forceinline__ float silu_f(float x) { return x / (1.0f + __expf(-x)); }
__device__ __forceinline__ float sigm_f(float x) { return 1.0f / (1.0f + __expf(-x)); }

// ---------------------------------------------------------------------------
// Kernel 1: per-node projections through the sender/receiver blocks of We1.
// FsP[n][j] = sum_k feat[n][k] * We1[8+k][j] ; FrP[n][j] = ... We1[136+k][j]
// ---------------------------------------------------------------------------
__global__ __launch_bounds__(128)
void k_proj(const float* __restrict__ feat, const float* __restrict__ We1,
            float* __restrict__ FsP, float* __restrict__ FrP)
{
    __shared__ float sF[128];
    int n = blockIdx.x, j = threadIdx.x;
    sF[j] = feat[n * 128 + j];
    __syncthreads();
    float a = 0.f, b = 0.f;
    #pragma unroll 8
    for (int k = 0; k < 128; ++k) {
        float f = sF[k];
        a = fmaf(f, We1[(8   + k) * 128 + j], a);
        b = fmaf(f, We1[(136 + k) * 128 + j], b);
    }
    FsP[n * 128 + j] = a;
    FrP[n * 128 + j] = b;
}

// stage a contiguous 16x128 fp32 weight tile (2048 floats) into LDS
__device__ __forceinline__ void stage16x128(const float* __restrict__ gW, int kt,
                                            float* dst, int t)
{
    const float4* g4 = (const float4*)gW;
    float4* d4 = (float4*)dst;
    d4[t]       = g4[kt * 512 + t];
    d4[t + 256] = g4[kt * 512 + t + 256];
}

// sOut[r][c] = silu(scale * sum_k sIn[r][k] * gW[k][c]);  rows=32, cols=128, K=128
// sIn/sOut: [32][PAD] LDS; gW: [128][128] global; sW: 2x2048-float LDS dbuf.
// May be called with sOut == sIn (write happens after the final barrier).
__device__ __forceinline__ void gemm128(const float* sIn, const float* __restrict__ gW,
                                        float* sOut, float* sW, int t, float scale)
{
    const int g = t >> 5, c4 = (t & 31) * 4;
    float4 acc[4];
    #pragma unroll
    for (int i = 0; i < 4; ++i) acc[i] = make_float4(0.f, 0.f, 0.f, 0.f);

    stage16x128(gW, 0, sW, t);
    __syncthreads();
    #pragma unroll
    for (int kt = 0; kt < 8; ++kt) {
        float* cur = sW + (kt & 1) * 2048;
        if (kt < 7) stage16x128(gW, kt + 1, sW + ((kt & 1) ^ 1) * 2048, t);
        #pragma unroll
        for (int kk = 0; kk < 16; kk += 4) {
            const int kb = kt * 16 + kk;
            float4 a0 = *(const float4*)(sIn + (g +  0) * PAD + kb);
            float4 a1 = *(const float4*)(sIn + (g +  8) * PAD + kb);
            float4 a2 = *(const float4*)(sIn + (g + 16) * PAD + kb);
            float4 a3 = *(const float4*)(sIn + (g + 24) * PAD + kb);
#define STEP(Q, COMP) { \
            const float4 w = *(const float4*)(cur + (kk + Q) * 128 + c4); \
            acc[0].x = fmaf(a0.COMP, w.x, acc[0].x); acc[0].y = fmaf(a0.COMP, w.y, acc[0].y); \
            acc[0].z = fmaf(a0.COMP, w.z, acc[0].z); acc[0].w = fmaf(a0.COMP, w.w, acc[0].w); \
            acc[1].x = fmaf(a1.COMP, w.x, acc[1].x); acc[1].y = fmaf(a1.COMP, w.y, acc[1].y); \
            acc[1].z = fmaf(a1.COMP, w.z, acc[1].z); acc[1].w = fmaf(a1.COMP, w.w, acc[1].w); \
            acc[2].x = fmaf(a2.COMP, w.x, acc[2].x); acc[2].y = fmaf(a2.COMP, w.y, acc[2].y); \
            acc[2].z = fmaf(a2.COMP, w.z, acc[2].z); acc[2].w = fmaf(a2.COMP, w.w, acc[2].w); \
            acc[3].x = fmaf(a3.COMP, w.x, acc[3].x); acc[3].y = fmaf(a3.COMP, w.y, acc[3].y); \
            acc[3].z = fmaf(a3.COMP, w.z, acc[3].z); acc[3].w = fmaf(a3.COMP, w.w, acc[3].w); }
            STEP(0, x) STEP(1, y) STEP(2, z) STEP(3, w)
#undef STEP
        }
        __syncthreads();
    }
    #pragma unroll
    for (int i = 0; i < 4; ++i) {
        int r = g + 8 * i;
        float4 v = acc[i];
        v.x = silu_f(v.x * scale); v.y = silu_f(v.y * scale);
        v.z = silu_f(v.z * scale); v.w = silu_f(v.w * scale);
        *(float4*)(sOut + r * PAD + c4) = v;
    }
}

// g[r][v*8+w] = sum_u phi[r][u] * Wtp[u][v*8+w];  rows=32, cols=64, K=128
__device__ __forceinline__ void gemm_tp(const float* sIn, const float* __restrict__ gW,
                                        float* sG, float* sW, int t)
{
    const int rg = t >> 4, c4 = (t & 15) * 4;
    float4 acc0 = make_float4(0.f, 0.f, 0.f, 0.f), acc1 = acc0;
    const float4* g4 = (const float4*)gW;
    ((float4*)sW)[t] = g4[t];
    __syncthreads();
    #pragma unroll
    for (int kt = 0; kt < 8; ++kt) {
        float* cur = sW + (kt & 1) * 1024;
        if (kt < 7) ((float4*)(sW + ((kt & 1) ^ 1) * 1024))[t] = g4[(kt + 1) * 256 + t];
        #pragma unroll
        for (int kk = 0; kk < 16; kk += 4) {
            const int kb = kt * 16 + kk;
            float4 a0 = *(const float4*)(sIn + rg * PAD + kb);
            float4 a1 = *(const float4*)(sIn + (rg + 16) * PAD + kb);
#define STEP(Q, COMP) { \
            const float4 w = *(const float4*)(cur + (kk + Q) * 64 + c4); \
            acc0.x = fmaf(a0.COMP, w.x, acc0.x); acc0.y = fmaf(a0.COMP, w.y, acc0.y); \
            acc0.z = fmaf(a0.COMP, w.z, acc0.z); acc0.w = fmaf(a0.COMP, w.w, acc0.w); \
            acc1.x = fmaf(a1.COMP, w.x, acc1.x); acc1.y = fmaf(a1.COMP, w.y, acc1.y); \
            acc1.z = fmaf(a1.COMP, w.z, acc1.z); acc1.w = fmaf(a1.COMP, w.w, acc1.w); }
            STEP(0, x) STEP(1, y) STEP(2, z) STEP(3, w)
#undef STEP
        }
        __syncthreads();
    }
    *(float4*)(sG + rg * 64 + c4)        = acc0;
    *(float4*)(sG + (rg + 16) * 64 + c4) = acc1;
}

// ---------------------------------------------------------------------------
// Kernel 2: one block per sender; loops receivers in chunks of 32.
// ---------------------------------------------------------------------------
__global__ __launch_bounds__(256)
void k_edge(const float* __restrict__ pos,
            const float* __restrict__ We1,
            const float* __restrict__ We2,
            const float* __restrict__ Wx1,
            const float* __restrict__ Wx2,
            const float* __restrict__ Winf,
            const float* __restrict__ Wtp,
            const float* __restrict__ FsP,
            const float* __restrict__ FrP,
            float* __restrict__ MI,
            float* __restrict__ VEC)
{
    __shared__ float sA[CH * PAD];      // activations ping
    __shared__ float sB[CH * PAD];      // m_ij (kept live through the chunk)
    __shared__ float sW[4096];          // weight-tile double buffer
    __shared__ float sG[CH * 64];       // TP output g
    __shared__ float sSh[CH * NV * 3];  // sh1
    __shared__ float sLen[CH * NV];
    __shared__ float sWlen[NV * 128];   // We1 rows 0..7
    __shared__ float sFsP[128];
    __shared__ float sWinf[128];
    __shared__ float sPosS[24];
    __shared__ float sE[CH];
    __shared__ float sDot[CH * 8];
    __shared__ float sPart[8 * 24];
    __shared__ float sMiAcc[256];

    const int s = blockIdx.x;
    const int t = threadIdx.x;

    if (t < 128) { sFsP[t] = FsP[s * 128 + t]; sWinf[t] = Winf[t]; }
    if (t < 24)  sPosS[t] = pos[s * 24 + t];
    {   // We1 rows 0..7 are the first 1024 floats
        int idx = t;
        #pragma unroll
        for (int u = 0; u < 4; ++u, idx += 256) sWlen[idx] = We1[idx];
    }
    float miacc = 0.f;   // partial of m_i[s][t&127] over rows r = (t>>7), (t>>7)+2, ...
    float vacc  = 0.f;   // threads 0..23: vec accumulator for (w=t%8, k=t/8)
    __syncthreads();

    for (int c = 0; c < NCH; ++c) {
        const int r0 = c * CH;
        // ---- phase 0: lengths + sh1 (one (r,v) pair per thread) ----
        {
            int r = t >> 3, v = t & 7;
            const float* pr = pos + (size_t)(r0 + r) * 24 + v * 3;
            float dx = sPosS[v * 3 + 0] - pr[0];
            float dy = sPosS[v * 3 + 1] - pr[1];
            float dz = sPosS[v * 3 + 2] - pr[2];
            float sq  = dx * dx + dy * dy + dz * dz;
            float len = sqrtf(fmaxf(sq, 1e-20f));   // r==s -> dx=0 exactly -> sh1=0
            float inv = SQRT3 / len;
            sLen[r * 8 + v] = len;
            sSh[(r * 8 + v) * 3 + 0] = dx * inv;
            sSh[(r * 8 + v) * 3 + 1] = dy * inv;
            sSh[(r * 8 + v) * 3 + 2] = dz * inv;
        }
        __syncthreads();
        // ---- phase 1: a1 = silu(C1*(len@We1[0:8] + FsP[s] + FrP[r])) -> sA ----
        {
            int g = t >> 5, c4 = (t & 31) * 4;
            float4 fs = *(const float4*)(sFsP + c4);
            #pragma unroll
            for (int i = 0; i < 4; ++i) {
                int r = g + 8 * i;
                float4 a = make_float4(0.f, 0.f, 0.f, 0.f);
                #pragma unroll
                for (int v = 0; v < 8; ++v) {
                    float l = sLen[r * 8 + v];
                    float4 w = *(const float4*)(sWlen + v * 128 + c4);
                    a.x = fmaf(l, w.x, a.x); a.y = fmaf(l, w.y, a.y);
                    a.z = fmaf(l, w.z, a.z); a.w = fmaf(l, w.w, a.w);
                }
                float4 fr = *(const float4*)(FrP + (size_t)(r0 + r) * 128 + c4);
                float4 o;
                o.x = silu_f((a.x + fs.x + fr.x) * C1);
                o.y = silu_f((a.y + fs.y + fr.y) * C1);
                o.z = silu_f((a.z + fs.z + fr.z) * C1);
                o.w = silu_f((a.w + fs.w + fr.w) * C1);
                *(float4*)(sA + r * PAD + c4) = o;
            }
        }
        // ---- phase 2: m_ij -> sB ----
        gemm128(sA, We2, sB, sW, t, C2);
        __syncthreads();
        // ---- phase e: e[r] = sigmoid(C2 * dot(m, Winf)), masked at r==s ----
        {
            int r = t >> 3, o = t & 7;
            float d = 0.f;
            #pragma unroll
            for (int k = 0; k < 16; ++k)
                d = fmaf(sB[r * PAD + o * 16 + k], sWinf[o * 16 + k], d);
            sDot[r * 8 + o] = d;
        }
        __syncthreads();
        if (t < CH) {
            float d = 0.f;
            #pragma unroll
            for (int o = 0; o < 8; ++o) d += sDot[t * 8 + o];
            sE[t] = (r0 + t == s) ? 0.f : sigm_f(d * C2);
        }
        __syncthreads();
        // ---- phase mi: register-accumulate m_i ----
        {
            int j = t & 127, h = t >> 7;
            #pragma unroll
            for (int r = h; r < CH; r += 2)
                miacc = fmaf(sB[r * PAD + j], sE[r], miacc);
        }
        // ---- phases 3/4: phi_x MLP (in-place safe: writes after final barrier) ----
        gemm128(sB, Wx1, sA, sW, t, C2);
        gemm128(sA, Wx2, sA, sW, t, C2);
        // ---- phase 5: g = phi @ Wtp -> sG ----
        gemm_tp(sA, Wtp, sG, sW, t);
        __syncthreads();
        // ---- phase 7: vec partials: sum_r sum_v g[r][v*8+w] * sh1[r][v][k] ----
        if (t < 192) {
            int w = t & 7, kc = (t >> 3) % 3, rg = t / 24;
            float sum = 0.f;
            #pragma unroll
            for (int rr = 0; rr < 4; ++rr) {
                int r = rg * 4 + rr;
                #pragma unroll
                for (int v = 0; v < 8; ++v)
                    sum = fmaf(sG[r * 64 + v * 8 + w], sSh[(r * 8 + v) * 3 + kc], sum);
            }
            sPart[rg * 24 + kc * 8 + w] = sum;
        }
        __syncthreads();
        if (t < 24) {
            float sum = 0.f;
            #pragma unroll
            for (int rg = 0; rg < 8; ++rg) sum += sPart[rg * 24 + t];
            vacc += sum * (1.0f / 32.0f);   // / sqrt(U*V) = /32
        }
        __syncthreads();
    }

    // ---- epilogue: write m_i[s][:] and vec[s][:] ----
    {
        int j = t & 127, h = t >> 7;
        sMiAcc[h * 128 + j] = miacc;
    }
    __syncthreads();
    if (t < 128) MI[s * 128 + t] = sMiAcc[t] + sMiAcc[128 + t];
    if (t < 24) {
        int w = t & 7, kc = t >> 3;
        VEC[s * 24 + w * 3 + kc] = vacc;
    }
}

// ---------------------------------------------------------------------------
// Kernel 3: per-node h-MLP + residual + position update.
// ---------------------------------------------------------------------------
__global__ __launch_bounds__(128)
void k_node(const float* __restrict__ pos, const float* __restrict__ feat,
            const float* __restrict__ Wh1, const float* __restrict__ Wh2,
            const float* __restrict__ Wh3,
            const float* __restrict__ MI, const float* __restrict__ VEC,
            float* __restrict__ outPos, float* __restrict__ outFeat)
{
    __shared__ float sMi[128], sF[128], sH[128];
    int n = blockIdx.x, j = threadIdx.x;
    sMi[j] = MI[n * 128 + j];
    sF[j]  = feat[n * 128 + j];
    __syncthreads();
    float a = 0.f;
    #pragma unroll 8
    for (int k = 0; k < 128; ++k) a = fmaf(sMi[k], Wh1[k * 128 + j], a);
    #pragma unroll 8
    for (int k = 0; k < 128; ++k) a = fmaf(sF[k], Wh1[(128 + k) * 128 + j], a);
    a = silu_f(a * 0.0625f);            // 1/sqrt(256)
    sH[j] = a;
    __syncthreads();
    float b = 0.f;
    #pragma unroll 8
    for (int k = 0; k < 128; ++k) b = fmaf(sH[k], Wh2[k * 128 + j], b);
    b = silu_f(b * C2);
    sMi[j] = b;                         // reuse (loop1 readers are past the barrier)
    __syncthreads();
    float cc = 0.f;
    #pragma unroll 8
    for (int k = 0; k < 128; ++k) cc = fmaf(sMi[k], Wh3[k * 128 + j], cc);
    outFeat[n * 128 + j] = cc * C2 + sF[j];
    if (j < 24) outPos[n * 24 + j] = pos[n * 24 + j] + VEC[n * 24 + j];
}

// ---------------------------------------------------------------------------
extern "C" void kernel_launch(void* const* d_in, const int* in_sizes, int n_in,
                              void* d_out, int out_size, void* d_ws, size_t ws_size,
                              hipStream_t stream) {
    const float* pos  = (const float*)d_in[0];
    const float* feat = (const float*)d_in[1];
    const float* We1  = (const float*)d_in[2];
    const float* We2  = (const float*)d_in[3];
    const float* Wx1  = (const float*)d_in[4];
    const float* Wx2  = (const float*)d_in[5];
    const float* Winf = (const float*)d_in[6];
    const float* Wtp  = (const float*)d_in[7];
    const float* Wh1  = (const float*)d_in[8];
    const float* Wh2  = (const float*)d_in[9];
    const float* Wh3  = (const float*)d_in[10];

    float* outPos  = (float*)d_out;              // [512*8*3]
    float* outFeat = (float*)d_out + NN * 24;    // [512*128]

    float* ws  = (float*)d_ws;
    float* FsP = ws;                  // 65536 floats
    float* FrP = ws + 65536;          // 65536
    float* MI  = ws + 131072;         // 65536
    float* VEC = ws + 196608;         // 12288  (total 816 KB)

    k_proj<<<dim3(NN), dim3(128), 0, stream>>>(feat, We1, FsP, FrP);
    k_edge<<<dim3(NN), dim3(256), 0, stream>>>(pos, We1, We2, Wx1, Wx2, Winf, Wtp,
                                               FsP, FrP, MI, VEC);
    k_node<<<dim3(NN), dim3(128), 0, stream>>>(pos, feat, Wh1, Wh2, Wh3, MI, VEC,
                                               outPos, outFeat);
}

// Round 2
// 202.395 us; speedup vs baseline: 3.9694x; 3.9694x over previous
//
#include <hip/hip_runtime.h>
#include <math.h>

#define NN   512
#define NV   8
#define CH   32      // receivers per chunk
#define NCH  16      // chunks per sender (16*32 = 512 rows, r==s masked)

#define C1 0.06154574548966636f   // 1/sqrt(264)
#define C2 0.08838834764831845f   // 1/sqrt(128)
#define SQRT3 1.7320508075688772f

typedef __attribute__((ext_vector_type(8))) short bf16x8;   // 8 bf16 = 4 VGPRs
typedef __attribute__((ext_vector_type(4))) float f32x4;

__device__ __forceinline__ float silu_f(float x) { return x / (1.0f + __expf(-x)); }
__device__ __forceinline__ float sigm_f(float x) { return 1.0f / (1.0f + __expf(-x)); }

__device__ __forceinline__ short f2bf(float f) {   // RNE fp32 -> bf16 bits
    unsigned u = __builtin_bit_cast(unsigned, f);
    u = (u + 0x7FFFu + ((u >> 16) & 1u)) >> 16;
    return (short)u;
}
__device__ __forceinline__ float bf2f(short s) {
    unsigned u = ((unsigned)(unsigned short)s) << 16;
    return __builtin_bit_cast(float, u);
}

// activation LDS layout: 32 rows x 128 bf16, row stride 256B, XOR-swizzled
// 16B blocks so A-frag ds_read_b128 (16 lanes @ same col, rows 0..15) is ~2-way.
__device__ __forceinline__ int actswz(int r, int cb) {
    return r * 256 + (cb ^ ((r & 7) << 4));
}

// ---------------------------------------------------------------------------
// Pack a [128 x ncols] fp32 weight into MFMA B-fragment order (bf16):
// frag (ct, kt): lane holds W[kt*32 + (lane>>4)*8 + j][ct*16 + (lane&15)], j=0..7
// stored at out[((ct*4 + kt)*64 + lane)*8 + j]  -> k_edge loads are coalesced.
// ---------------------------------------------------------------------------
__global__ __launch_bounds__(256)
void k_pack(const float* __restrict__ W, short* __restrict__ out, int ncols)
{
    int idx = blockIdx.x * 256 + threadIdx.x;
    int lane = idx & 63, kt = (idx >> 6) & 3, ct = idx >> 8;
    if (ct * 16 >= ncols) return;
    int kg = lane >> 4, cl = lane & 15;
    bf16x8 v;
    #pragma unroll
    for (int j = 0; j < 8; ++j)
        v[j] = f2bf(W[(kt * 32 + kg * 8 + j) * ncols + ct * 16 + cl]);
    *(bf16x8*)(out + (size_t)idx * 8) = v;
}

// ---------------------------------------------------------------------------
// Kernel 1: per-node projections through the sender/receiver blocks of We1.
// ---------------------------------------------------------------------------
__global__ __launch_bounds__(128)
void k_proj(const float* __restrict__ feat, const float* __restrict__ We1,
            float* __restrict__ FsP, float* __restrict__ FrP)
{
    __shared__ float sF[128];
    int n = blockIdx.x, j = threadIdx.x;
    sF[j] = feat[n * 128 + j];
    __syncthreads();
    float a = 0.f, b = 0.f;
    #pragma unroll 8
    for (int k = 0; k < 128; ++k) {
        float f = sF[k];
        a = fmaf(f, We1[(8   + k) * 128 + j], a);
        b = fmaf(f, We1[(136 + k) * 128 + j], b);
    }
    FsP[n * 128 + j] = a;
    FrP[n * 128 + j] = b;
}

// ---------------------------------------------------------------------------
// 32x128 = (32x128 bf16 LDS) @ (128x128 weights in VGPR frags), silu(scale*),
// bf16 result scattered back to LDS. Per wave: cols [w*32, w*32+32).
// KEEP: also return the silu'd fp32 accumulators (for m_i accumulation).
// ---------------------------------------------------------------------------
template<bool KEEP>
__device__ __forceinline__ void gemm_b(const short* sInS, short* sOutS,
                                       const bf16x8 (&B)[2][4],
                                       int rl, int kg, int w, float scale,
                                       f32x4 (&keep)[2][2])
{
    const char* sIn = (const char*)sInS;
    char* sOut = (char*)sOutS;
    f32x4 acc[2][2];
    #pragma unroll
    for (int rt = 0; rt < 2; ++rt)
        #pragma unroll
        for (int ctl = 0; ctl < 2; ++ctl) {
            acc[rt][ctl][0] = 0.f; acc[rt][ctl][1] = 0.f;
            acc[rt][ctl][2] = 0.f; acc[rt][ctl][3] = 0.f;
        }
    #pragma unroll
    for (int kt = 0; kt < 4; ++kt) {
        bf16x8 a0 = *(const bf16x8*)(sIn + actswz(rl,      kt * 64 + kg * 16));
        bf16x8 a1 = *(const bf16x8*)(sIn + actswz(rl + 16, kt * 64 + kg * 16));
        acc[0][0] = __builtin_amdgcn_mfma_f32_16x16x32_bf16(a0, B[0][kt], acc[0][0], 0, 0, 0);
        acc[0][1] = __builtin_amdgcn_mfma_f32_16x16x32_bf16(a0, B[1][kt], acc[0][1], 0, 0, 0);
        acc[1][0] = __builtin_amdgcn_mfma_f32_16x16x32_bf16(a1, B[0][kt], acc[1][0], 0, 0, 0);
        acc[1][1] = __builtin_amdgcn_mfma_f32_16x16x32_bf16(a1, B[1][kt], acc[1][1], 0, 0, 0);
    }
    // D layout: row = rt*16 + (lane>>4)*4 + jj, col = w*32 + ctl*16 + (lane&15)
    #pragma unroll
    for (int rt = 0; rt < 2; ++rt)
        #pragma unroll
        for (int ctl = 0; ctl < 2; ++ctl)
            #pragma unroll
            for (int jj = 0; jj < 4; ++jj) {
                float v = silu_f(acc[rt][ctl][jj] * scale);
                if (KEEP) keep[rt][ctl][jj] = v;
                int r = rt * 16 + kg * 4 + jj;
                int c = w * 32 + ctl * 16 + rl;
                *(short*)(sOut + actswz(r, 2 * c)) = f2bf(v);
            }
}

// 32x64 = (32x128 bf16 LDS) @ (128x64 Wtp frags); fp32 result to sG[32][66].
__device__ __forceinline__ void gemm_tpm(const short* sInS, float* sG,
                                         const bf16x8 (&B)[4],
                                         int rl, int kg, int w)
{
    const char* sIn = (const char*)sInS;
    f32x4 acc[2];
    #pragma unroll
    for (int rt = 0; rt < 2; ++rt) {
        acc[rt][0] = 0.f; acc[rt][1] = 0.f; acc[rt][2] = 0.f; acc[rt][3] = 0.f;
    }
    #pragma unroll
    for (int kt = 0; kt < 4; ++kt) {
        bf16x8 a0 = *(const bf16x8*)(sIn + actswz(rl,      kt * 64 + kg * 16));
        bf16x8 a1 = *(const bf16x8*)(sIn + actswz(rl + 16, kt * 64 + kg * 16));
        acc[0] = __builtin_amdgcn_mfma_f32_16x16x32_bf16(a0, B[kt], acc[0], 0, 0, 0);
        acc[1] = __builtin_amdgcn_mfma_f32_16x16x32_bf16(a1, B[kt], acc[1], 0, 0, 0);
    }
    #pragma unroll
    for (int rt = 0; rt < 2; ++rt)
        #pragma unroll
        for (int jj = 0; jj < 4; ++jj)
            sG[(rt * 16 + kg * 4 + jj) * 66 + w * 16 + rl] = acc[rt][jj];
}

// ---------------------------------------------------------------------------
// Kernel 2: one block per sender; 16 chunks of 32 receivers, MFMA cores.
// ---------------------------------------------------------------------------
__global__ __launch_bounds__(256, 2)
void k_edge(const float* __restrict__ pos,
            const float* __restrict__ We1,
            const float* __restrict__ Winf,
            const float* __restrict__ FsP,
            const float* __restrict__ FrP,
            const short* __restrict__ We2p,
            const short* __restrict__ Wx1p,
            const short* __restrict__ Wx2p,
            const short* __restrict__ Wtpp,
            float* __restrict__ MI,
            float* __restrict__ VEC)
{
    __shared__ __align__(16) short sX[CH * 128];   // act ping (bf16, swizzled)
    __shared__ __align__(16) short sY[CH * 128];   // act pong
    __shared__ float sG[CH * 66];                  // TP output (padded)
    __shared__ float sSh[CH * NV * 3];
    __shared__ float sLen[CH * NV];
    __shared__ float sWlen[NV * 128];              // We1 rows 0..7
    __shared__ float sFsP[128];
    __shared__ float sWinf[128];
    __shared__ float sPosS[24];
    __shared__ float sE[CH];
    __shared__ float sDot[CH * 8];
    __shared__ float sPart[8 * 24];

    const int s = blockIdx.x, t = threadIdx.x;
    const int lane = t & 63, w = t >> 6;
    const int rl = lane & 15, kg = lane >> 4;

    if (t < 128) { sFsP[t] = FsP[s * 128 + t]; sWinf[t] = Winf[t]; }
    if (t < 24)  sPosS[t] = pos[s * 24 + t];
    {
        int idx = t;
        #pragma unroll
        for (int u = 0; u < 4; ++u, idx += 256) sWlen[idx] = We1[idx];
    }

    // --- persistent per-wave weight fragments (loaded once, reused 16x) ---
    const bf16x8* pWe2 = (const bf16x8*)We2p;
    const bf16x8* pWx1 = (const bf16x8*)Wx1p;
    const bf16x8* pWx2 = (const bf16x8*)Wx2p;
    const bf16x8* pWtp = (const bf16x8*)Wtpp;
    bf16x8 Bwe2[2][4], Bwx1[2][4], Bwx2[2][4], Btp[4];
    #pragma unroll
    for (int ctl = 0; ctl < 2; ++ctl)
        #pragma unroll
        for (int kt = 0; kt < 4; ++kt) {
            int fi = ((w * 2 + ctl) * 4 + kt) * 64 + lane;
            Bwe2[ctl][kt] = pWe2[fi];
            Bwx1[ctl][kt] = pWx1[fi];
            Bwx2[ctl][kt] = pWx2[fi];
        }
    #pragma unroll
    for (int kt = 0; kt < 4; ++kt) Btp[kt] = pWtp[(w * 4 + kt) * 64 + lane];

    float miacc0 = 0.f, miacc1 = 0.f, vacc = 0.f;
    __syncthreads();

    const float4 fsa = *(const float4*)(sFsP + (t & 15) * 8);
    const float4 fsb = *(const float4*)(sFsP + (t & 15) * 8 + 4);

    for (int c = 0; c < NCH; ++c) {
        const int r0 = c * CH;
        // ---- ph0: lengths + sh1 ----
        {
            int r = t >> 3, v = t & 7;
            const float* pr = pos + (size_t)(r0 + r) * 24 + v * 3;
            float dx = sPosS[v * 3 + 0] - pr[0];
            float dy = sPosS[v * 3 + 1] - pr[1];
            float dz = sPosS[v * 3 + 2] - pr[2];
            float sq  = dx * dx + dy * dy + dz * dz;
            float len = sqrtf(fmaxf(sq, 1e-20f));   // r==s -> sh1 = 0 exactly
            float inv = SQRT3 / len;
            sLen[r * 8 + v] = len;
            sSh[(r * 8 + v) * 3 + 0] = dx * inv;
            sSh[(r * 8 + v) * 3 + 1] = dy * inv;
            sSh[(r * 8 + v) * 3 + 2] = dz * inv;
        }
        __syncthreads();                                               // B1
        // ---- ph1: a1 = silu(C1*(len@We1[0:8] + FsP[s] + FrP[r])) -> sX bf16 ----
        {
            int cg = t & 15, c0 = cg * 8;
            #pragma unroll
            for (int it = 0; it < 2; ++it) {
                int r = (t >> 4) + it * 16;
                const float4* fr4 = (const float4*)(FrP + (size_t)(r0 + r) * 128 + c0);
                float4 a0 = fr4[0], a1 = fr4[1];
                a0.x += fsa.x; a0.y += fsa.y; a0.z += fsa.z; a0.w += fsa.w;
                a1.x += fsb.x; a1.y += fsb.y; a1.z += fsb.z; a1.w += fsb.w;
                #pragma unroll
                for (int v = 0; v < 8; ++v) {
                    float l = sLen[r * 8 + v];
                    const float4* wr = (const float4*)(sWlen + v * 128 + c0);
                    float4 w0 = wr[0], w1 = wr[1];
                    a0.x = fmaf(l, w0.x, a0.x); a0.y = fmaf(l, w0.y, a0.y);
                    a0.z = fmaf(l, w0.z, a0.z); a0.w = fmaf(l, w0.w, a0.w);
                    a1.x = fmaf(l, w1.x, a1.x); a1.y = fmaf(l, w1.y, a1.y);
                    a1.z = fmaf(l, w1.z, a1.z); a1.w = fmaf(l, w1.w, a1.w);
                }
                bf16x8 o;
                o[0] = f2bf(silu_f(a0.x * C1)); o[1] = f2bf(silu_f(a0.y * C1));
                o[2] = f2bf(silu_f(a0.z * C1)); o[3] = f2bf(silu_f(a0.w * C1));
                o[4] = f2bf(silu_f(a1.x * C1)); o[5] = f2bf(silu_f(a1.y * C1));
                o[6] = f2bf(silu_f(a1.z * C1)); o[7] = f2bf(silu_f(a1.w * C1));
                *(bf16x8*)((char*)sX + actswz(r, c0 * 2)) = o;
            }
        }
        __syncthreads();                                               // B2
        // ---- m_ij = silu(C2 * a1 @ We2) -> sY ; keep fp32 in accM ----
        f32x4 accM[2][2];
        gemm_b<true>(sX, sY, Bwe2, rl, kg, w, C2, accM);
        __syncthreads();                                               // B3
        // ---- e[r] = sigmoid(C2 * m_ij . Winf) ----
        {
            int r = t >> 3, o = t & 7;
            const char* sYc = (const char*)sY;
            bf16x8 m0 = *(const bf16x8*)(sYc + actswz(r, o * 32));
            bf16x8 m1 = *(const bf16x8*)(sYc + actswz(r, o * 32 + 16));
            float d = 0.f;
            #pragma unroll
            for (int j = 0; j < 8; ++j) {
                d = fmaf(bf2f(m0[j]), sWinf[o * 16 + j], d);
                d = fmaf(bf2f(m1[j]), sWinf[o * 16 + 8 + j], d);
            }
            sDot[r * 8 + o] = d;
        }
        __syncthreads();                                               // B4
        if (t < CH) {
            float d = 0.f;
            #pragma unroll
            for (int o = 0; o < 8; ++o) d += sDot[t * 8 + o];
            sE[t] = (r0 + t == s) ? 0.f : sigm_f(d * C2);
        }
        __syncthreads();                                               // B5
        // ---- m_i accumulation from MFMA registers ----
        #pragma unroll
        for (int rt = 0; rt < 2; ++rt)
            #pragma unroll
            for (int jj = 0; jj < 4; ++jj) {
                float e = sE[rt * 16 + kg * 4 + jj];
                miacc0 = fmaf(accM[rt][0][jj], e, miacc0);
                miacc1 = fmaf(accM[rt][1][jj], e, miacc1);
            }
        // ---- phi_x MLP ----
        gemm_b<false>(sY, sX, Bwx1, rl, kg, w, C2, accM);
        __syncthreads();                                               // B6
        gemm_b<false>(sX, sY, Bwx2, rl, kg, w, C2, accM);
        __syncthreads();                                               // B7
        // ---- g = phi_x @ Wtp -> sG ----
        gemm_tpm(sY, sG, Btp, rl, kg, w);
        __syncthreads();                                               // B8
        // ---- vec partials: sum_r sum_v g[r][v*8+wv] * sh1[r][v][kc] ----
        if (t < 192) {
            int wv = t & 7, kc = (t >> 3) % 3, rg = t / 24;
            float sum = 0.f;
            #pragma unroll
            for (int rr = 0; rr < 4; ++rr) {
                int r = rg * 4 + rr;
                #pragma unroll
                for (int v = 0; v < 8; ++v)
                    sum = fmaf(sG[r * 66 + v * 8 + wv], sSh[(r * 8 + v) * 3 + kc], sum);
            }
            sPart[rg * 24 + kc * 8 + wv] = sum;
        }
        __syncthreads();                                               // B9
        if (t < 24) {
            float sum = 0.f;
            #pragma unroll
            for (int rg = 0; rg < 8; ++rg) sum += sPart[rg * 24 + t];
            vacc += sum * (1.0f / 32.0f);   // / sqrt(U*V)
        }
    }

    // ---- epilogue: reduce m_i across lane-groups (rows) and write ----
    miacc0 += __shfl_xor(miacc0, 16); miacc0 += __shfl_xor(miacc0, 32);
    miacc1 += __shfl_xor(miacc1, 16); miacc1 += __shfl_xor(miacc1, 32);
    if (lane < 16) {
        MI[s * 128 + w * 32 + lane]      = miacc0;
        MI[s * 128 + w * 32 + 16 + lane] = miacc1;
    }
    if (t < 24) {
        int wv = t & 7, kc = t >> 3;
        VEC[s * 24 + wv * 3 + kc] = vacc;
    }
}

// ---------------------------------------------------------------------------
// Kernel 3: per-node h-MLP + residual + position update.
// ---------------------------------------------------------------------------
__global__ __launch_bounds__(128)
void k_node(const float* __restrict__ pos, const float* __restrict__ feat,
            const float* __restrict__ Wh1, const float* __restrict__ Wh2,
            const float* __restrict__ Wh3,
            const float* __restrict__ MI, const float* __restrict__ VEC,
            float* __restrict__ outPos, float* __restrict__ outFeat)
{
    __shared__ float sMi[128], sF[128], sH[128];
    int n = blockIdx.x, j = threadIdx.x;
    sMi[j] = MI[n * 128 + j];
    sF[j]  = feat[n * 128 + j];
    __syncthreads();
    float a = 0.f;
    #pragma unroll 8
    for (int k = 0; k < 128; ++k) a = fmaf(sMi[k], Wh1[k * 128 + j], a);
    #pragma unroll 8
    for (int k = 0; k < 128; ++k) a = fmaf(sF[k], Wh1[(128 + k) * 128 + j], a);
    a = silu_f(a * 0.0625f);            // 1/sqrt(256)
    sH[j] = a;
    __syncthreads();
    float b = 0.f;
    #pragma unroll 8
    for (int k = 0; k < 128; ++k) b = fmaf(sH[k], Wh2[k * 128 + j], b);
    b = silu_f(b * C2);
    sMi[j] = b;
    __syncthreads();
    float cc = 0.f;
    #pragma unroll 8
    for (int k = 0; k < 128; ++k) cc = fmaf(sMi[k], Wh3[k * 128 + j], cc);
    outFeat[n * 128 + j] = cc * C2 + sF[j];
    if (j < 24) outPos[n * 24 + j] = pos[n * 24 + j] + VEC[n * 24 + j];
}

// ---------------------------------------------------------------------------
extern "C" void kernel_launch(void* const* d_in, const int* in_sizes, int n_in,
                              void* d_out, int out_size, void* d_ws, size_t ws_size,
                              hipStream_t stream) {
    const float* pos  = (const float*)d_in[0];
    const float* feat = (const float*)d_in[1];
    const float* We1  = (const float*)d_in[2];
    const float* We2  = (const float*)d_in[3];
    const float* Wx1  = (const float*)d_in[4];
    const float* Wx2  = (const float*)d_in[5];
    const float* Winf = (const float*)d_in[6];
    const float* Wtp  = (const float*)d_in[7];
    const float* Wh1  = (const float*)d_in[8];
    const float* Wh2  = (const float*)d_in[9];
    const float* Wh3  = (const float*)d_in[10];

    float* outPos  = (float*)d_out;              // [512*8*3]
    float* outFeat = (float*)d_out + NN * 24;    // [512*128]

    float* ws  = (float*)d_ws;
    float* FsP = ws;                   // 65536 floats
    float* FrP = ws + 65536;           // 65536
    float* MI  = ws + 131072;          // 65536
    float* VEC = ws + 196608;          // 12288
    short* wpack = (short*)(ws + 208896);
    short* We2p = wpack;               // 16384 shorts
    short* Wx1p = wpack + 16384;       // 16384
    short* Wx2p = wpack + 32768;       // 16384
    short* Wtpp = wpack + 49152;       // 8192  (total ws ~950 KB)

    k_pack<<<dim3(8), dim3(256), 0, stream>>>(We2, We2p, 128);
    k_pack<<<dim3(8), dim3(256), 0, stream>>>(Wx1, Wx1p, 128);
    k_pack<<<dim3(8), dim3(256), 0, stream>>>(Wx2, Wx2p, 128);
    k_pack<<<dim3(4), dim3(256), 0, stream>>>(Wtp, Wtpp, 64);
    k_proj<<<dim3(NN), dim3(128), 0, stream>>>(feat, We1, FsP, FrP);
    k_edge<<<dim3(NN), dim3(256), 0, stream>>>(pos, We1, Winf, FsP, FrP,
                                               We2p, Wx1p, Wx2p, Wtpp, MI, VEC);
    k_node<<<dim3(NN), dim3(128), 0, stream>>>(pos, feat, Wh1, Wh2, Wh3, MI, VEC,
                                               outPos, outFeat);
}

// Round 3
// 195.658 us; speedup vs baseline: 4.1061x; 1.0344x over previous
//
#include <hip/hip_runtime.h>
#include <math.h>

#define NN   512
#define NV   8
#define CH   32      // receivers per chunk
#define NCHH 8       // chunks per half-block (2 blocks per sender)

#define C1 0.06154574548966636f   // 1/sqrt(264)
#define C2 0.08838834764831845f   // 1/sqrt(128)
#define SQRT3 1.7320508075688772f

typedef __attribute__((ext_vector_type(8))) short bf16x8;   // 8 bf16 = 4 VGPRs
typedef __attribute__((ext_vector_type(4))) float f32x4;

#define MFMA16 __builtin_amdgcn_mfma_f32_16x16x32_bf16

__device__ __forceinline__ float silu_f(float x) { return x / (1.0f + __expf(-x)); }
__device__ __forceinline__ float sigm_f(float x) { return 1.0f / (1.0f + __expf(-x)); }

__device__ __forceinline__ short f2bf(float f) {   // RNE fp32 -> bf16 bits
    unsigned u = __builtin_bit_cast(unsigned, f);
    u = (u + 0x7FFFu + ((u >> 16) & 1u)) >> 16;
    return (short)u;
}
__device__ __forceinline__ float bf2f(short s) {
    unsigned u = ((unsigned)(unsigned short)s) << 16;
    return __builtin_bit_cast(float, u);
}

// ---------------------------------------------------------------------------
// Pack a [128 x ncols] fp32 weight into MFMA B-fragment order (bf16):
// frag (ct, kt): lane holds W[kt*32 + (lane>>4)*8 + j][ct*16 + (lane&15)], j=0..7
// ---------------------------------------------------------------------------
__global__ __launch_bounds__(256)
void k_pack(const float* __restrict__ W, short* __restrict__ out, int ncols)
{
    int idx = blockIdx.x * 256 + threadIdx.x;
    int lane = idx & 63, kt = (idx >> 6) & 3, ct = idx >> 8;
    if (ct * 16 >= ncols) return;
    int kg = lane >> 4, cl = lane & 15;
    bf16x8 v;
    #pragma unroll
    for (int j = 0; j < 8; ++j)
        v[j] = f2bf(W[(kt * 32 + kg * 8 + j) * ncols + ct * 16 + cl]);
    *(bf16x8*)(out + (size_t)idx * 8) = v;
}

// ---------------------------------------------------------------------------
// Kernel 1: per-node projections through the sender/receiver blocks of We1.
// ---------------------------------------------------------------------------
__global__ __launch_bounds__(128)
void k_proj(const float* __restrict__ feat, const float* __restrict__ We1,
            float* __restrict__ FsP, float* __restrict__ FrP)
{
    __shared__ float sF[128];
    int n = blockIdx.x, j = threadIdx.x;
    sF[j] = feat[n * 128 + j];
    __syncthreads();
    float a = 0.f, b = 0.f;
    #pragma unroll 8
    for (int k = 0; k < 128; ++k) {
        float f = sF[k];
        a = fmaf(f, We1[(8   + k) * 128 + j], a);
        b = fmaf(f, We1[(136 + k) * 128 + j], b);
    }
    FsP[n * 128 + j] = a;
    FrP[n * 128 + j] = b;
}

// ---------------------------------------------------------------------------
// streamed B-fragment loader (coalesced 16B/lane from packed layout, L2-hot)
// ---------------------------------------------------------------------------
__device__ __forceinline__ void loadB(const short* __restrict__ p,
                                      bf16x8 (&B)[2][4], int w, int lane)
{
    const bf16x8* p8 = (const bf16x8*)p;
    #pragma unroll
    for (int ctl = 0; ctl < 2; ++ctl)
        #pragma unroll
        for (int kt = 0; kt < 4; ++kt)
            B[ctl][kt] = p8[((w * 2 + ctl) * 4 + kt) * 64 + lane];
}

// 32x128 @ 128x128 core: A from swizzled bf16 LDS, B in VGPRs, silu(scale*x),
// bf16 scatter back to LDS. Per wave: cols [w*32, w*32+32).
template<bool KEEP>
__device__ __forceinline__ void gemm_core(const short* sIn_, short* sOut_,
                                          const bf16x8 (&B)[2][4],
                                          const int (&adrK)[4],
                                          const int (&wAdr)[2][4],
                                          float scale, f32x4 (&keep)[2][2])
{
    const char* sIn = (const char*)sIn_;
    char* sOut = (char*)sOut_;
    const f32x4 z = {0.f, 0.f, 0.f, 0.f};
    f32x4 acc[2][2] = {{z, z}, {z, z}};
    #pragma unroll
    for (int kt = 0; kt < 4; ++kt) {
        bf16x8 a0 = *(const bf16x8*)(sIn + adrK[kt]);
        bf16x8 a1 = *(const bf16x8*)(sIn + adrK[kt] + 4096);
        acc[0][0] = MFMA16(a0, B[0][kt], acc[0][0], 0, 0, 0);
        acc[0][1] = MFMA16(a0, B[1][kt], acc[0][1], 0, 0, 0);
        acc[1][0] = MFMA16(a1, B[0][kt], acc[1][0], 0, 0, 0);
        acc[1][1] = MFMA16(a1, B[1][kt], acc[1][1], 0, 0, 0);
    }
    #pragma unroll
    for (int rt = 0; rt < 2; ++rt)
        #pragma unroll
        for (int ctl = 0; ctl < 2; ++ctl)
            #pragma unroll
            for (int jj = 0; jj < 4; ++jj) {
                float v = silu_f(acc[rt][ctl][jj] * scale);
                if (KEEP) keep[rt][ctl][jj] = v;
                *(short*)(sOut + wAdr[ctl][jj] + rt * 4096) = f2bf(v);
            }
}

// ---------------------------------------------------------------------------
// Kernel 2: one block per (sender, half); 8 chunks of 32 receivers.
// ---------------------------------------------------------------------------
__global__ __launch_bounds__(256, 4)
void k_edge(const float* __restrict__ pos,
            const float* __restrict__ We1,
            const float* __restrict__ Winf,
            const float* __restrict__ FsP,
            const float* __restrict__ FrP,
            const short* __restrict__ We2p,
            const short* __restrict__ Wx1p,
            const short* __restrict__ Wx2p,
            const short* __restrict__ Wtpp,
            float* __restrict__ MI2,
            float* __restrict__ VEC2)
{
    __shared__ __align__(16) short sX[CH * 128];   // activations ping (swizzled)
    __shared__ __align__(16) short sY[CH * 128];   // activations pong
    __shared__ __align__(16) float sLS[CH * NV * 4]; // (sh.xyz, len), v-slot swizzled
    __shared__ float sWinf[8 * 17];                // stride-17 (conflict-free)
    __shared__ float sPosS[24];
    __shared__ float sE[CH];
    __shared__ float sVp[4 * 24];

    const int bid = blockIdx.x;
    const int s = bid >> 1, half = bid & 1;
    const int t = threadIdx.x;
    const int lane = t & 63, w = t >> 6;
    const int rl = lane & 15, kg = lane >> 4;

    // ---- per-thread constant LDS byte addresses (hoisted out of the loop) ----
    const int swz = (rl & 7) << 4;
    const int ktperm = (rl & 4) << 4;                 // swz bit 6
    const int baseRd = rl * 256 + ((kg * 16) ^ (swz & 0x30));
    int adrK[4];
    #pragma unroll
    for (int kt = 0; kt < 4; ++kt) adrK[kt] = baseRd + ((kt * 64) ^ ktperm);
    int wAdr[2][4];
    #pragma unroll
    for (int ctl = 0; ctl < 2; ++ctl)
        #pragma unroll
        for (int jj = 0; jj < 4; ++jj) {
            int r = kg * 4 + jj;
            wAdr[ctl][jj] = r * 256 + ((w * 64 + ctl * 32 + 2 * rl) ^ ((r & 7) << 4));
        }
    const int colg0 = w * 32 + rl, colg1 = colg0 + 16;
    const int er = t >> 3, eo = t & 7;
    const int eAdr0 = er * 256 + ((eo * 32)      ^ ((er & 7) << 4));
    const int eAdr1 = er * 256 + ((eo * 32 + 16) ^ ((er & 7) << 4));
    const int vv = w * 2 + (rl >> 3);                 // TP phase: fixed v per lane

    if (t < 128) sWinf[(t >> 4) * 17 + (t & 15)] = Winf[t];
    if (t < 24)  sPosS[t] = pos[s * 24 + t];

    // ---- pinned fragments: We2 (32 VGPR) + length-GEMM B (8 VGPR) ----
    bf16x8 Bwe2[2][4];
    loadB(We2p, Bwe2, w, lane);
    bf16x8 Blen[2];
    #pragma unroll
    for (int ctl = 0; ctl < 2; ++ctl) {
        int col = w * 32 + ctl * 16 + rl;
        bf16x8 b = {0, 0, 0, 0, 0, 0, 0, 0};
        if (kg == 0) {
            #pragma unroll
            for (int j = 0; j < 8; ++j) b[j] = f2bf(We1[j * 128 + col]);
        } else if (kg == 1) {
            b[0] = f2bf(FsP[s * 128 + col]);   // k=8 slot carries +FsP[s]
        }
        Blen[ctl] = b;
    }

    float miacc0 = 0.f, miacc1 = 0.f;
    float vax = 0.f, vay = 0.f, vaz = 0.f;
    __syncthreads();                                              // B0

    for (int c = 0; c < NCHH; ++c) {
        const int r0 = (half * NCHH + c) * CH;

        // ---- FrP prefetch in D-layout (16 scalar loads, L2-hot) ----
        float frv[2][2][4];
        #pragma unroll
        for (int rt = 0; rt < 2; ++rt)
            #pragma unroll
            for (int jj = 0; jj < 4; ++jj) {
                const float* fp = FrP + (size_t)(r0 + rt * 16 + kg * 4 + jj) * 128;
                frv[rt][0][jj] = fp[colg0];
                frv[rt][1][jj] = fp[colg1];
            }

        // ---- ph0: lengths + sh1 -> sLS (v-slot swizzled float4) ----
        {
            int r = t >> 3, v = t & 7;
            const float* pr = pos + (size_t)(r0 + r) * 24 + v * 3;
            float dx = sPosS[v * 3 + 0] - pr[0];
            float dy = sPosS[v * 3 + 1] - pr[1];
            float dz = sPosS[v * 3 + 2] - pr[2];
            float sq  = dx * dx + dy * dy + dz * dz;
            float len = sqrtf(fmaxf(sq, 1e-20f));   // r==s -> dx=0 -> sh1=0
            float inv = SQRT3 / len;
            f32x4 o; o[0] = dx * inv; o[1] = dy * inv; o[2] = dz * inv; o[3] = len;
            *(f32x4*)(sLS + (r * 8 + (v ^ (r & 7))) * 4) = o;
        }
        __syncthreads();                                          // B1

        // ---- length-GEMM via MFMA (K padded to 32; k=8 slot = +FsP) ----
        {
            bf16x8 aL0 = {0,0,0,0,0,0,0,0}, aL1 = {0,0,0,0,0,0,0,0};
            if (kg == 0) {
                const float* Lp = sLS + rl * 32;
                const float* Lq = sLS + (rl + 16) * 32;
                #pragma unroll
                for (int j = 0; j < 8; ++j) {
                    aL0[j] = f2bf(Lp[(j ^ (rl & 7)) * 4 + 3]);
                    aL1[j] = f2bf(Lq[(j ^ (rl & 7)) * 4 + 3]);
                }
            } else if (kg == 1) {
                aL0[0] = (short)0x3F80;  aL1[0] = (short)0x3F80;   // 1.0bf
            }
            const f32x4 z = {0.f, 0.f, 0.f, 0.f};
            f32x4 aP[2][2];
            aP[0][0] = MFMA16(aL0, Blen[0], z, 0, 0, 0);
            aP[0][1] = MFMA16(aL0, Blen[1], z, 0, 0, 0);
            aP[1][0] = MFMA16(aL1, Blen[0], z, 0, 0, 0);
            aP[1][1] = MFMA16(aL1, Blen[1], z, 0, 0, 0);
            char* sXc = (char*)sX;
            #pragma unroll
            for (int rt = 0; rt < 2; ++rt)
                #pragma unroll
                for (int ctl = 0; ctl < 2; ++ctl)
                    #pragma unroll
                    for (int jj = 0; jj < 4; ++jj) {
                        float val = (aP[rt][ctl][jj] + frv[rt][ctl][jj]) * C1;
                        *(short*)(sXc + wAdr[ctl][jj] + rt * 4096) = f2bf(silu_f(val));
                    }
        }
        __syncthreads();                                          // B2

        // ---- m_ij = silu(C2 * a1 @ We2) -> sY ; keep fp32 copies ----
        f32x4 keepM[2][2];
        gemm_core<true>(sX, sY, Bwe2, adrK, wAdr, C2, keepM);
        __syncthreads();                                          // B3

        // ---- e[r] = sigmoid(C2 * m_ij . Winf)  (in-wave shfl reduce) ----
        {
            const char* sYc = (const char*)sY;
            bf16x8 m0 = *(const bf16x8*)(sYc + eAdr0);
            bf16x8 m1 = *(const bf16x8*)(sYc + eAdr1);
            float d = 0.f;
            #pragma unroll
            for (int j = 0; j < 8; ++j) {
                d = fmaf(bf2f(m0[j]), sWinf[eo * 17 + j],     d);
                d = fmaf(bf2f(m1[j]), sWinf[eo * 17 + 8 + j], d);
            }
            d += __shfl_xor(d, 1); d += __shfl_xor(d, 2); d += __shfl_xor(d, 4);
            if (eo == 0) sE[er] = (r0 + er == s) ? 0.f : sigm_f(d * C2);
        }
        __syncthreads();                                          // B5

        // ---- m_i accumulation from registers ----
        #pragma unroll
        for (int rt = 0; rt < 2; ++rt)
            #pragma unroll
            for (int jj = 0; jj < 4; ++jj) {
                float e = sE[rt * 16 + kg * 4 + jj];
                miacc0 = fmaf(keepM[rt][0][jj], e, miacc0);
                miacc1 = fmaf(keepM[rt][1][jj], e, miacc1);
            }

        // ---- phi_x layer 1 (streamed Wx1) ----
        {
            bf16x8 Bs[2][4];
            loadB(Wx1p, Bs, w, lane);
            gemm_core<false>(sY, sX, Bs, adrK, wAdr, C2, keepM);
        }
        __syncthreads();                                          // B6
        // ---- phi_x layer 2 (streamed Wx2) ----
        {
            bf16x8 Bs[2][4];
            loadB(Wx2p, Bs, w, lane);
            gemm_core<false>(sX, sY, Bs, adrK, wAdr, C2, keepM);
        }
        __syncthreads();                                          // B7

        // ---- TP gemm (streamed Wtp, per-wave 16 cols) + vec acc from regs ----
        {
            bf16x8 Bt[4];
            const bf16x8* p8 = (const bf16x8*)Wtpp;
            #pragma unroll
            for (int kt = 0; kt < 4; ++kt) Bt[kt] = p8[(w * 4 + kt) * 64 + lane];
            const f32x4 z = {0.f, 0.f, 0.f, 0.f};
            f32x4 acc0 = z, acc1 = z;
            const char* sYc = (const char*)sY;
            #pragma unroll
            for (int kt = 0; kt < 4; ++kt) {
                bf16x8 a0 = *(const bf16x8*)(sYc + adrK[kt]);
                bf16x8 a1 = *(const bf16x8*)(sYc + adrK[kt] + 4096);
                acc0 = MFMA16(a0, Bt[kt], acc0, 0, 0, 0);
                acc1 = MFMA16(a1, Bt[kt], acc1, 0, 0, 0);
            }
            #pragma unroll
            for (int rt = 0; rt < 2; ++rt)
                #pragma unroll
                for (int jj = 0; jj < 4; ++jj) {
                    int row = rt * 16 + kg * 4 + jj;
                    const f32x4 sh = *(const f32x4*)(sLS + (row * 8 + (vv ^ (row & 7))) * 4);
                    float g = rt ? acc1[jj] : acc0[jj];
                    vax = fmaf(g, sh[0], vax);
                    vay = fmaf(g, sh[1], vay);
                    vaz = fmaf(g, sh[2], vaz);
                }
        }
        __syncthreads();                                          // B8
    }

    // ---- epilogue: m_i reduce over row-groups ----
    miacc0 += __shfl_xor(miacc0, 16); miacc0 += __shfl_xor(miacc0, 32);
    miacc1 += __shfl_xor(miacc1, 16); miacc1 += __shfl_xor(miacc1, 32);
    if (lane < 16) {
        float* mo = MI2 + (size_t)(half * NN + s) * 128;
        mo[w * 32 + lane]      = miacc0;
        mo[w * 32 + 16 + lane] = miacc1;
    }
    // ---- vec reduce: over rl&8 (v-pair) then kg groups ----
    vax += __shfl_xor(vax, 8);  vay += __shfl_xor(vay, 8);  vaz += __shfl_xor(vaz, 8);
    vax += __shfl_xor(vax, 16); vay += __shfl_xor(vay, 16); vaz += __shfl_xor(vaz, 16);
    vax += __shfl_xor(vax, 32); vay += __shfl_xor(vay, 32); vaz += __shfl_xor(vaz, 32);
    if ((lane & 56) == 0) {     // lanes 0..7: wv = lane
        float* vp = sVp + w * 24 + lane * 3;
        vp[0] = vax; vp[1] = vay; vp[2] = vaz;
    }
    __syncthreads();
    if (t < 24) {
        float sum = sVp[t] + sVp[24 + t] + sVp[48 + t] + sVp[72 + t];
        VEC2[(size_t)(half * NN + s) * 24 + t] = sum * (1.0f / 32.0f);
    }
}

// ---------------------------------------------------------------------------
// Kernel 3: per-node h-MLP + residual + position update (sums the 2 halves).
// ---------------------------------------------------------------------------
__global__ __launch_bounds__(128)
void k_node(const float* __restrict__ pos, const float* __restrict__ feat,
            const float* __restrict__ Wh1, const float* __restrict__ Wh2,
            const float* __restrict__ Wh3,
            const float* __restrict__ MI2, const float* __restrict__ VEC2,
            float* __restrict__ outPos, float* __restrict__ outFeat)
{
    __shared__ float sMi[128], sF[128], sH[128];
    int n = blockIdx.x, j = threadIdx.x;
    sMi[j] = MI2[n * 128 + j] + MI2[NN * 128 + n * 128 + j];
    sF[j]  = feat[n * 128 + j];
    __syncthreads();
    float a = 0.f;
    #pragma unroll 8
    for (int k = 0; k < 128; ++k) a = fmaf(sMi[k], Wh1[k * 128 + j], a);
    #pragma unroll 8
    for (int k = 0; k < 128; ++k) a = fmaf(sF[k], Wh1[(128 + k) * 128 + j], a);
    a = silu_f(a * 0.0625f);            // 1/sqrt(256)
    sH[j] = a;
    __syncthreads();
    float b = 0.f;
    #pragma unroll 8
    for (int k = 0; k < 128; ++k) b = fmaf(sH[k], Wh2[k * 128 + j], b);
    b = silu_f(b * C2);
    sMi[j] = b;
    __syncthreads();
    float cc = 0.f;
    #pragma unroll 8
    for (int k = 0; k < 128; ++k) cc = fmaf(sMi[k], Wh3[k * 128 + j], cc);
    outFeat[n * 128 + j] = cc * C2 + sF[j];
    if (j < 24) outPos[n * 24 + j] = pos[n * 24 + j]
                                   + VEC2[n * 24 + j] + VEC2[NN * 24 + n * 24 + j];
}

// ---------------------------------------------------------------------------
extern "C" void kernel_launch(void* const* d_in, const int* in_sizes, int n_in,
                              void* d_out, int out_size, void* d_ws, size_t ws_size,
                              hipStream_t stream) {
    const float* pos  = (const float*)d_in[0];
    const float* feat = (const float*)d_in[1];
    const float* We1  = (const float*)d_in[2];
    const float* We2  = (const float*)d_in[3];
    const float* Wx1  = (const float*)d_in[4];
    const float* Wx2  = (const float*)d_in[5];
    const float* Winf = (const float*)d_in[6];
    const float* Wtp  = (const float*)d_in[7];
    const float* Wh1  = (const float*)d_in[8];
    const float* Wh2  = (const float*)d_in[9];
    const float* Wh3  = (const float*)d_in[10];

    float* outPos  = (float*)d_out;              // [512*8*3]
    float* outFeat = (float*)d_out + NN * 24;    // [512*128]

    float* ws   = (float*)d_ws;
    float* FsP  = ws;                   // 65536 floats
    float* FrP  = ws + 65536;           // 65536
    float* MI2  = ws + 131072;          // 2*65536
    float* VEC2 = ws + 262144;          // 2*12288
    short* wpack = (short*)(ws + 286720);
    short* We2p = wpack;                // 16384 shorts
    short* Wx1p = wpack + 16384;        // 16384
    short* Wx2p = wpack + 32768;        // 16384
    short* Wtpp = wpack + 49152;        // 8192   (total ws ~1.21 MB)

    k_pack<<<dim3(8), dim3(256), 0, stream>>>(We2, We2p, 128);
    k_pack<<<dim3(8), dim3(256), 0, stream>>>(Wx1, Wx1p, 128);
    k_pack<<<dim3(8), dim3(256), 0, stream>>>(Wx2, Wx2p, 128);
    k_pack<<<dim3(4), dim3(256), 0, stream>>>(Wtp, Wtpp, 64);
    k_proj<<<dim3(NN), dim3(128), 0, stream>>>(feat, We1, FsP, FrP);
    k_edge<<<dim3(2 * NN), dim3(256), 0, stream>>>(pos, We1, Winf, FsP, FrP,
                                                   We2p, Wx1p, Wx2p, Wtpp, MI2, VEC2);
    k_node<<<dim3(NN), dim3(128), 0, stream>>>(pos, feat, Wh1, Wh2, Wh3, MI2, VEC2,
                                               outPos, outFeat);
}